// Round 1
// baseline (321.363 us; speedup 1.0000x reference)
//
#include <hip/hip_runtime.h>
#include <cstddef>

typedef float f32x4 __attribute__((ext_vector_type(4)));
typedef __bf16 bf16x8 __attribute__((ext_vector_type(8)));
typedef unsigned short u16;
typedef unsigned short u16x4 __attribute__((ext_vector_type(4)));

__device__ __forceinline__ u16 f2bf(float f) {
  unsigned u = __builtin_bit_cast(unsigned, f);
  u += 0x7FFFu + ((u >> 16) & 1u);   // RNE round to bf16
  return (u16)(u >> 16);
}
__device__ __forceinline__ float bf2f(u16 b) {
  unsigned u = ((unsigned)b) << 16;
  return __builtin_bit_cast(float, u);
}
__device__ __forceinline__ float sigf(float x) { return 1.0f / (1.0f + __expf(-x)); }
__device__ __forceinline__ float tanhfast(float x) { return 1.0f - 2.0f / (__expf(2.0f * x) + 1.0f); }

// ---------------------------------------------------------------------------
// K1: xproj[dir][m][n] = e(tok[m]) . wih[dir][n][:] + bih[n] + bhh[n]
//     m in [0,4096) = b*128+l, n in [0,400), K=300. Gather fused into A-stage.
//     64x64 tile, fp32 VALU, LDS staged transposed [k][m].
// ---------------------------------------------------------------------------
__global__ __launch_bounds__(256) void k1_xproj(
    const int* __restrict__ tok1, const int* __restrict__ tok2,
    const float* __restrict__ embed,
    const float* __restrict__ wihA, const float* __restrict__ wihB,
    const float* __restrict__ wihC, const float* __restrict__ wihD,
    const float* __restrict__ bihA, const float* __restrict__ bihB,
    const float* __restrict__ bihC, const float* __restrict__ bihD,
    const float* __restrict__ bhhA, const float* __restrict__ bhhB,
    const float* __restrict__ bhhC, const float* __restrict__ bhhD,
    float* __restrict__ xproj)
{
  __shared__ __align__(16) float aL[16][68];  // stride 68 -> 272B rows, 16B aligned
  __shared__ __align__(16) float bL[16][68];
  const int dir = blockIdx.z;
  const float* wih = (dir == 0) ? wihA : (dir == 1) ? wihB : (dir == 2) ? wihC : wihD;
  const float* bih = (dir == 0) ? bihA : (dir == 1) ? bihB : (dir == 2) ? bihC : bihD;
  const float* bhh = (dir == 0) ? bhhA : (dir == 1) ? bhhB : (dir == 2) ? bhhC : bhhD;
  const int* tok = (dir < 2) ? tok1 : tok2;
  const int mb = blockIdx.x * 64, nb = blockIdx.y * 64;
  const int tid = threadIdx.x;
  const int ms = tid & 63, kq = tid >> 6;  // staging: row ms, k-quad kq
  const int tx = tid & 15, ty = tid >> 4;  // compute: 4x4 micro-tile
  const long arow = (long)tok[mb + ms] * 300;
  const int ns = nb + ms;
  const bool bval = (ns < 400);
  float acc[4][4] = {};

  for (int kb = 0; kb < 300; kb += 16) {
    const int k = kb + kq * 4;
    f32x4 av = {0.f, 0.f, 0.f, 0.f}, bv = {0.f, 0.f, 0.f, 0.f};
    if (k + 4 <= 300) {
      av = *(const f32x4*)(embed + arow + k);
      if (bval) bv = *(const f32x4*)(wih + (long)ns * 300 + k);
    } else {
      #pragma unroll
      for (int u = 0; u < 4; ++u)
        if (k + u < 300) {
          av[u] = embed[arow + k + u];
          if (bval) bv[u] = wih[(long)ns * 300 + k + u];
        }
    }
    __syncthreads();  // previous slab fully consumed
    #pragma unroll
    for (int u = 0; u < 4; ++u) { aL[kq * 4 + u][ms] = av[u]; bL[kq * 4 + u][ms] = bv[u]; }
    __syncthreads();
    #pragma unroll
    for (int kk = 0; kk < 16; ++kk) {
      const f32x4 a4 = *(const f32x4*)&aL[kk][ty * 4];
      const f32x4 b4 = *(const f32x4*)&bL[kk][tx * 4];
      #pragma unroll
      for (int i = 0; i < 4; ++i)
        #pragma unroll
        for (int j = 0; j < 4; ++j) acc[i][j] += a4[i] * b4[j];
    }
  }
  float bias[4];
  #pragma unroll
  for (int j = 0; j < 4; ++j) {
    const int n = nb + tx * 4 + j;
    bias[j] = (n < 400) ? (bih[n] + bhh[n]) : 0.f;
  }
  #pragma unroll
  for (int i = 0; i < 4; ++i) {
    const long m = mb + ty * 4 + i;
    float* orow = xproj + ((long)dir * 4096 + m) * 400;
    #pragma unroll
    for (int j = 0; j < 4; ++j) {
      const int n = nb + tx * 4 + j;
      if (n < 400) orow[n] = acc[i][j] + bias[j];
    }
  }
}

// ---------------------------------------------------------------------------
// K2: recurrent LSTM. One workgroup per (b, dir); 256 threads; each thread owns
// rows r0=tid, r1=tid+256 of whh (fp32 in registers). h broadcast via LDS.
// Gate order i,f,g,o. bwd dirs read/write time index 127-t.
// ---------------------------------------------------------------------------
__global__ __launch_bounds__(256, 1) void k2_lstm(
    const float* __restrict__ xproj,
    const float* __restrict__ whhA, const float* __restrict__ whhB,
    const float* __restrict__ whhC, const float* __restrict__ whhD,
    u16* __restrict__ s1e, u16* __restrict__ s2e)
{
  const int b = blockIdx.x, dir = blockIdx.y;
  const float* whh = (dir == 0) ? whhA : (dir == 1) ? whhB : (dir == 2) ? whhC : whhD;
  const int tid = threadIdx.x;
  __shared__ __align__(16) float hL[104];
  __shared__ float gL[400];
  const int r0 = tid, r1 = tid + 256;
  const bool v1 = (r1 < 400);
  float w0[100], w1[100];
  {
    const f32x4* p0 = (const f32x4*)(whh + (long)r0 * 100);
    #pragma unroll
    for (int q = 0; q < 25; ++q) {
      const f32x4 t = p0[q];
      w0[q * 4 + 0] = t[0]; w0[q * 4 + 1] = t[1]; w0[q * 4 + 2] = t[2]; w0[q * 4 + 3] = t[3];
    }
    if (v1) {
      const f32x4* p1 = (const f32x4*)(whh + (long)r1 * 100);
      #pragma unroll
      for (int q = 0; q < 25; ++q) {
        const f32x4 t = p1[q];
        w1[q * 4 + 0] = t[0]; w1[q * 4 + 1] = t[1]; w1[q * 4 + 2] = t[2]; w1[q * 4 + 3] = t[3];
      }
    } else {
      #pragma unroll
      for (int q = 0; q < 100; ++q) w1[q] = 0.f;
    }
  }
  const bool bwd = (dir & 1);
  const float* xq = xproj + ((long)dir * 4096 + (long)b * 128) * 400;
  u16* se = ((dir < 2) ? s1e : s2e) + (long)b * 128 * 200 + (bwd ? 100 : 0);
  float c = 0.f;
  if (tid < 104) hL[tid] = 0.f;
  const int ta0 = bwd ? 127 : 0;
  float xn0 = xq[ta0 * 400 + r0];
  float xn1 = v1 ? xq[ta0 * 400 + r1] : 0.f;
  __syncthreads();

  for (int t = 0; t < 128; ++t) {
    float acc0 = xn0, acc1 = xn1;
    const int tn = t + 1;
    if (tn < 128) {  // prefetch next step's xproj (independent of h)
      const int ta = bwd ? (127 - tn) : tn;
      xn0 = xq[ta * 400 + r0];
      xn1 = v1 ? xq[ta * 400 + r1] : 0.f;
    }
    #pragma unroll
    for (int q = 0; q < 25; ++q) {
      const f32x4 h4 = *(const f32x4*)&hL[q * 4];
      acc0 += w0[q * 4 + 0] * h4[0]; acc0 += w0[q * 4 + 1] * h4[1];
      acc0 += w0[q * 4 + 2] * h4[2]; acc0 += w0[q * 4 + 3] * h4[3];
      acc1 += w1[q * 4 + 0] * h4[0]; acc1 += w1[q * 4 + 1] * h4[1];
      acc1 += w1[q * 4 + 2] * h4[2]; acc1 += w1[q * 4 + 3] * h4[3];
    }
    gL[r0] = acc0;
    if (v1) gL[r1] = acc1;
    __syncthreads();
    if (tid < 100) {
      const float gi = gL[tid], gf = gL[tid + 100], gg = gL[tid + 200], go = gL[tid + 300];
      c = sigf(gf) * c + sigf(gi) * tanhfast(gg);
      const float h = sigf(go) * tanhfast(c);
      hL[tid] = h;
      const int ta = bwd ? (127 - t) : t;
      se[ta * 200 + tid] = f2bf(h);
    }
    __syncthreads();
  }
}

// ---------------------------------------------------------------------------
// K3: reciprocal norms rn[sent][b][l][w*20+p] = 1/max(||bf16(s_d*W_pd)||, 1e-8)
//     Rounding matches K4's staging exactly.
// ---------------------------------------------------------------------------
__global__ __launch_bounds__(256) void k3_norms(
    const u16* __restrict__ s1e, const u16* __restrict__ s2e,
    const float* __restrict__ W1, const float* __restrict__ W2,
    float* __restrict__ rn)
{
  const int b = blockIdx.x, lc = blockIdx.y, sent = blockIdx.z;
  const u16* se = sent ? s2e : s1e;
  #pragma unroll
  for (int it = 0; it < 5; ++it) {
    const int idx = it * 256 + (int)threadIdx.x;  // < 1280
    const int l = lc * 32 + idx / 40;
    const int pw = idx % 40;
    const float* Wp = (pw < 20) ? (W1 + pw * 200) : (W2 + (pw - 20) * 200);
    const u16* srow = se + ((long)b * 128 + l) * 200;
    float acc = 0.f;
    #pragma unroll 10
    for (int q = 0; q < 50; ++q) {
      const u16x4 sv = *(const u16x4*)(srow + q * 4);
      const f32x4 wv = *(const f32x4*)(Wp + q * 4);
      #pragma unroll
      for (int u = 0; u < 4; ++u) {
        const float pr = bf2f(f2bf(bf2f(sv[u]) * wv[u]));
        acc += pr * pr;
      }
    }
    rn[(((long)sent * 32 + b) * 128 + l) * 40 + pw] = 1.f / fmaxf(sqrtf(acc), 1e-8f);
  }
}

// ---------------------------------------------------------------------------
// K4: matching. Per (b,p,w): C = (s1.Wp)(s2.Wp)^T via 16x16x32 bf16 MFMA,
//     scale by rnu_i*rnv_j, rowmax -> s1{f,b}, colmax -> s2{f,b}.
//     LDS row stride 232 elems (464 B): 2-way bank alias only (free).
// ---------------------------------------------------------------------------
#define LDSS 232
__global__ __launch_bounds__(256, 1) void k4_match(
    const u16* __restrict__ s1e, const u16* __restrict__ s2e,
    const float* __restrict__ W1, const float* __restrict__ W2,
    const float* __restrict__ rn, float* __restrict__ out)
{
  __shared__ __align__(16) u16 aLb[128 * LDSS];
  __shared__ __align__(16) u16 bLb[128 * LDSS];
  __shared__ float rnuL[128], rnvL[128];
  __shared__ float redA[2][128], redB[2][128];
  const int b = blockIdx.x, p = blockIdx.y, w = blockIdx.z;
  const int tid = threadIdx.x;
  const float* Wp = (w ? W2 : W1) + p * 200;
  const u16* s1r = s1e + (long)b * 128 * 200;
  const u16* s2r = s2e + (long)b * 128 * 200;

  // stage scaled bf16 tiles (zero-pad k in [200,224))
  for (int idx = tid; idx < 128 * 56; idx += 256) {
    const int row = idx / 56;
    const int k = (idx % 56) * 4;
    u16x4 oa = {0, 0, 0, 0}, ob = {0, 0, 0, 0};
    if (k < 200) {
      const u16x4 sa = *(const u16x4*)(s1r + row * 200 + k);
      const u16x4 sb = *(const u16x4*)(s2r + row * 200 + k);
      const f32x4 wv = *(const f32x4*)(Wp + k);
      #pragma unroll
      for (int u = 0; u < 4; ++u) {
        oa[u] = f2bf(bf2f(sa[u]) * wv[u]);
        ob[u] = f2bf(bf2f(sb[u]) * wv[u]);
      }
    }
    *(u16x4*)(aLb + row * LDSS + k) = oa;
    *(u16x4*)(bLb + row * LDSS + k) = ob;
  }
  if (tid < 128) {
    const int pw = w * 20 + p;
    rnuL[tid] = rn[(((long)0 * 32 + b) * 128 + tid) * 40 + pw];
    rnvL[tid] = rn[(((long)1 * 32 + b) * 128 + tid) * 40 + pw];
  }
  __syncthreads();

  const int lane = tid & 63, wvid = tid >> 6;
  const int wr = wvid >> 1, wc = wvid & 1;  // wave quadrant in 2x2
  const int lr = lane & 15, kg = lane >> 4;
  f32x4 acc[4][4];
  #pragma unroll
  for (int mt = 0; mt < 4; ++mt)
    #pragma unroll
    for (int nt = 0; nt < 4; ++nt) acc[mt][nt] = 0.f;

  const u16* a0 = aLb + (64 * wr + lr) * LDSS + kg * 8;
  const u16* b0 = bLb + (64 * wc + lr) * LDSS + kg * 8;
  #pragma unroll
  for (int ks = 0; ks < 7; ++ks) {
    bf16x8 af[4], bfv[4];
    #pragma unroll
    for (int mt = 0; mt < 4; ++mt) af[mt] = *(const bf16x8*)(a0 + mt * 16 * LDSS + ks * 32);
    #pragma unroll
    for (int nt = 0; nt < 4; ++nt) bfv[nt] = *(const bf16x8*)(b0 + nt * 16 * LDSS + ks * 32);
    #pragma unroll
    for (int mt = 0; mt < 4; ++mt)
      #pragma unroll
      for (int nt = 0; nt < 4; ++nt)
        acc[mt][nt] = __builtin_amdgcn_mfma_f32_16x16x32_bf16(af[mt], bfv[nt], acc[mt][nt], 0, 0, 0);
  }

  // epilogue: D[i][j]: i = 64*wr + mt*16 + kg*4 + r, j = 64*wc + nt*16 + lr
  float ru[4][4], rm[4][4], rv[4], cm[4];
  #pragma unroll
  for (int mt = 0; mt < 4; ++mt)
    #pragma unroll
    for (int r = 0; r < 4; ++r) {
      ru[mt][r] = rnuL[64 * wr + mt * 16 + kg * 4 + r];
      rm[mt][r] = -3.0e38f;
    }
  #pragma unroll
  for (int nt = 0; nt < 4; ++nt) { rv[nt] = rnvL[64 * wc + nt * 16 + lr]; cm[nt] = -3.0e38f; }
  #pragma unroll
  for (int mt = 0; mt < 4; ++mt)
    #pragma unroll
    for (int nt = 0; nt < 4; ++nt)
      #pragma unroll
      for (int r = 0; r < 4; ++r) {
        const float v = acc[mt][nt][r] * ru[mt][r] * rv[nt];
        rm[mt][r] = fmaxf(rm[mt][r], v);
        cm[nt] = fmaxf(cm[nt], v);
      }
  #pragma unroll
  for (int mt = 0; mt < 4; ++mt)
    #pragma unroll
    for (int r = 0; r < 4; ++r) {
      float v = rm[mt][r];
      v = fmaxf(v, __shfl_xor(v, 1, 64));
      v = fmaxf(v, __shfl_xor(v, 2, 64));
      v = fmaxf(v, __shfl_xor(v, 4, 64));
      v = fmaxf(v, __shfl_xor(v, 8, 64));
      rm[mt][r] = v;
    }
  #pragma unroll
  for (int nt = 0; nt < 4; ++nt) {
    float v = cm[nt];
    v = fmaxf(v, __shfl_xor(v, 16, 64));
    v = fmaxf(v, __shfl_xor(v, 32, 64));
    cm[nt] = v;
  }
  if (lr == 0) {
    #pragma unroll
    for (int mt = 0; mt < 4; ++mt)
      #pragma unroll
      for (int r = 0; r < 4; ++r) redA[wc][64 * wr + mt * 16 + kg * 4 + r] = rm[mt][r];
  }
  if (kg == 0) {
    #pragma unroll
    for (int nt = 0; nt < 4; ++nt) redB[wr][64 * wc + nt * 16 + lr] = cm[nt];
  }
  __syncthreads();
  if (tid < 128) {
    const float o1 = fmaxf(redA[0][tid], redA[1][tid]);  // max over j -> s1 side
    const float o2 = fmaxf(redB[0][tid], redB[1][tid]);  // max over i -> s2 side
    const long oi = ((long)b * 128 + tid) * 20 + p;
    out[(long)w * 81920 + oi] = o1;              // w=0: s1f, w=1: s1b
    out[163840 + (long)w * 81920 + oi] = o2;     // w=0: s2f, w=1: s2b
  }
}

// ---------------------------------------------------------------------------
extern "C" void kernel_launch(void* const* d_in, const int* in_sizes, int n_in,
                              void* d_out, int out_size, void* d_ws, size_t ws_size,
                              hipStream_t stream) {
  const int* tok1 = (const int*)d_in[0];
  const int* tok2 = (const int*)d_in[1];
  const float* embed = (const float*)d_in[2];
  // dirs: 0 = s1-fwd(lstm11 f), 1 = s1-bwd(lstm11 b), 2 = s2-fwd(lstm12 f), 3 = s2-bwd(lstm12 b)
  const float* wih0 = (const float*)d_in[3];
  const float* whh0 = (const float*)d_in[4];
  const float* bih0 = (const float*)d_in[5];
  const float* bhh0 = (const float*)d_in[6];
  const float* wih1 = (const float*)d_in[7];
  const float* whh1 = (const float*)d_in[8];
  const float* bih1 = (const float*)d_in[9];
  const float* bhh1 = (const float*)d_in[10];
  const float* wih2 = (const float*)d_in[11];
  const float* whh2 = (const float*)d_in[12];
  const float* bih2 = (const float*)d_in[13];
  const float* bhh2 = (const float*)d_in[14];
  const float* wih3 = (const float*)d_in[15];
  const float* whh3 = (const float*)d_in[16];
  const float* bih3 = (const float*)d_in[17];
  const float* bhh3 = (const float*)d_in[18];
  const float* W1 = (const float*)d_in[19];
  const float* W2 = (const float*)d_in[20];
  float* out = (float*)d_out;

  char* ws = (char*)d_ws;
  const size_t XPROJ_B = 26214400;   // 4*4096*400*4
  const size_t SE_B = 1638400;       // 32*128*200*2
  const size_t RN_B = 1310720;       // 2*32*128*40*4
  if (ws_size < XPROJ_B + 2 * SE_B + RN_B) return;
  float* xproj = (float*)ws;
  u16* s1e = (u16*)(ws + XPROJ_B);
  u16* s2e = (u16*)(ws + XPROJ_B + SE_B);
  float* rn = (float*)(ws + XPROJ_B + 2 * SE_B);

  k1_xproj<<<dim3(64, 7, 4), 256, 0, stream>>>(
      tok1, tok2, embed, wih0, wih1, wih2, wih3,
      bih0, bih1, bih2, bih3, bhh0, bhh1, bhh2, bhh3, xproj);
  k2_lstm<<<dim3(32, 4), 256, 0, stream>>>(xproj, whh0, whh1, whh2, whh3, s1e, s2e);
  k3_norms<<<dim3(32, 4, 2), 256, 0, stream>>>(s1e, s2e, W1, W2, rn);
  k4_match<<<dim3(32, 20, 2), 256, 0, stream>>>(s1e, s2e, W1, W2, rn, out);
}

// Round 2
// 308.112 us; speedup vs baseline: 1.0430x; 1.0430x over previous
//
#include <hip/hip_runtime.h>
#include <cstddef>

typedef float f32x4 __attribute__((ext_vector_type(4)));
typedef __bf16 bf16x8 __attribute__((ext_vector_type(8)));
typedef unsigned short u16;
typedef unsigned short u16x4 __attribute__((ext_vector_type(4)));

__device__ __forceinline__ u16 f2bf(float f) {
  unsigned u = __builtin_bit_cast(unsigned, f);
  u += 0x7FFFu + ((u >> 16) & 1u);   // RNE round to bf16
  return (u16)(u >> 16);
}
__device__ __forceinline__ float bf2f(u16 b) {
  unsigned u = ((unsigned)b) << 16;
  return __builtin_bit_cast(float, u);
}
__device__ __forceinline__ float sigf(float x) { return 1.0f / (1.0f + __expf(-x)); }
__device__ __forceinline__ float tanhfast(float x) { return 1.0f - 2.0f / (__expf(2.0f * x) + 1.0f); }

// Raw barrier: LDS-only drain (lgkmcnt), NO vmcnt drain -> global stores and
// prefetch loads stay in flight across the barrier. "memory" clobber orders
// the ds ops; sched_barrier(0) stops post-barrier code hoisting (rule #18).
__device__ __forceinline__ void wg_barrier() {
  asm volatile("s_waitcnt lgkmcnt(0)" ::: "memory");
  __builtin_amdgcn_s_barrier();
  __builtin_amdgcn_sched_barrier(0);
}

// ---------------------------------------------------------------------------
// K1: xproj[dir][m][n] = e(tok[m]) . wih[dir][n][:] + bih[n] + bhh[n]
//     bf16 MFMA 16x16x32, fp32 accumulate. Tile 128m x 64n, K=300 padded 320.
//     LDS stride 328 elems (656B): row->bank offset 4, 2-way alias only.
// ---------------------------------------------------------------------------
#define K1_LDA 328
__global__ __launch_bounds__(256) void k1_xproj(
    const int* __restrict__ tok1, const int* __restrict__ tok2,
    const float* __restrict__ embed,
    const float* __restrict__ wihA, const float* __restrict__ wihB,
    const float* __restrict__ wihC, const float* __restrict__ wihD,
    const float* __restrict__ bihA, const float* __restrict__ bihB,
    const float* __restrict__ bihC, const float* __restrict__ bihD,
    const float* __restrict__ bhhA, const float* __restrict__ bhhB,
    const float* __restrict__ bhhC, const float* __restrict__ bhhD,
    float* __restrict__ xproj)
{
  __shared__ __align__(16) u16 aL[128 * K1_LDA];
  __shared__ __align__(16) u16 bL[64 * K1_LDA];
  const int dir = blockIdx.z;
  const float* wih = (dir == 0) ? wihA : (dir == 1) ? wihB : (dir == 2) ? wihC : wihD;
  const float* bih = (dir == 0) ? bihA : (dir == 1) ? bihB : (dir == 2) ? bihC : bihD;
  const float* bhh = (dir == 0) ? bhhA : (dir == 1) ? bhhB : (dir == 2) ? bhhC : bhhD;
  const int* tok = (dir < 2) ? tok1 : tok2;
  const int mb = blockIdx.x * 128, nb = blockIdx.y * 64;
  const int tid = threadIdx.x;

  #pragma unroll
  for (int it = 0; it < 40; ++it) {            // A: 128 rows x 80 quad-chunks
    const int idx = it * 256 + tid;
    const int row = idx / 80, k = (idx % 80) * 4;
    u16x4 o = {0, 0, 0, 0};
    if (k < 300) {
      const long ar = (long)tok[mb + row] * 300;
      const f32x4 v = *(const f32x4*)(embed + ar + k);
      o[0] = f2bf(v[0]); o[1] = f2bf(v[1]); o[2] = f2bf(v[2]); o[3] = f2bf(v[3]);
    }
    *(u16x4*)(aL + row * K1_LDA + k) = o;
  }
  #pragma unroll
  for (int it = 0; it < 20; ++it) {            // B: 64 rows x 80 quad-chunks
    const int idx = it * 256 + tid;
    const int row = idx / 80, k = (idx % 80) * 4;
    const int n = nb + row;
    u16x4 o = {0, 0, 0, 0};
    if (k < 300 && n < 400) {
      const f32x4 v = *(const f32x4*)(wih + (long)n * 300 + k);
      o[0] = f2bf(v[0]); o[1] = f2bf(v[1]); o[2] = f2bf(v[2]); o[3] = f2bf(v[3]);
    }
    *(u16x4*)(bL + row * K1_LDA + k) = o;
  }
  __syncthreads();

  const int lane = tid & 63, wvid = tid >> 6;
  const int wr = wvid >> 1, wc = wvid & 1;     // wave covers 64m x 32n
  const int lr = lane & 15, kg = lane >> 4;
  f32x4 acc[4][2];
  #pragma unroll
  for (int mt = 0; mt < 4; ++mt)
    #pragma unroll
    for (int nt = 0; nt < 2; ++nt) acc[mt][nt] = 0.f;

  const u16* a0 = aL + (64 * wr + lr) * K1_LDA + kg * 8;
  const u16* b0 = bL + (32 * wc + lr) * K1_LDA + kg * 8;
  #pragma unroll
  for (int ks = 0; ks < 10; ++ks) {
    bf16x8 af[4], bfv[2];
    #pragma unroll
    for (int mt = 0; mt < 4; ++mt) af[mt] = *(const bf16x8*)(a0 + mt * 16 * K1_LDA + ks * 32);
    #pragma unroll
    for (int nt = 0; nt < 2; ++nt) bfv[nt] = *(const bf16x8*)(b0 + nt * 16 * K1_LDA + ks * 32);
    #pragma unroll
    for (int mt = 0; mt < 4; ++mt)
      #pragma unroll
      for (int nt = 0; nt < 2; ++nt)
        acc[mt][nt] = __builtin_amdgcn_mfma_f32_16x16x32_bf16(af[mt], bfv[nt], acc[mt][nt], 0, 0, 0);
  }

  #pragma unroll
  for (int nt = 0; nt < 2; ++nt) {
    const int n = nb + 32 * wc + 16 * nt + lr;
    if (n < 400) {
      const float bias = bih[n] + bhh[n];
      #pragma unroll
      for (int mt = 0; mt < 4; ++mt)
        #pragma unroll
        for (int r = 0; r < 4; ++r) {
          const int m = mb + 64 * wr + 16 * mt + 4 * kg + r;
          xproj[((long)dir * 4096 + m) * 400 + n] = acc[mt][nt][r] + bias;
        }
    }
  }
}

// ---------------------------------------------------------------------------
// K2: recurrent LSTM, fused gates + k-split.
//   thread (j, kh): rows {j, j+100, j+200, j+300} of whh over k-half kh
//   (kh0: k[0,48)+zero quad, kh1: k[48,100)). Partials combined via pL.
//   kh0 threads own c_j, do all gate math in-registers. 2 raw barriers/step,
//   no vmcnt drains. tid<128 -> kh0 (waves 0,1), tid>=128 -> kh1 (waves 2,3).
// ---------------------------------------------------------------------------
__global__ __launch_bounds__(256, 1) void k2_lstm(
    const float* __restrict__ xproj,
    const float* __restrict__ whhA, const float* __restrict__ whhB,
    const float* __restrict__ whhC, const float* __restrict__ whhD,
    u16* __restrict__ s1e, u16* __restrict__ s2e)
{
  const int b = blockIdx.x, dir = blockIdx.y;
  const float* whh = (dir == 0) ? whhA : (dir == 1) ? whhB : (dir == 2) ? whhC : whhD;
  const int tid = threadIdx.x;
  __shared__ __align__(16) float hL[104];
  __shared__ __align__(16) float pL[400];
  const int kh = tid >> 7;               // wave-uniform
  const int jr = tid & 127;
  const int jj = (jr < 100) ? jr : 99;   // clamp for safe addressing
  const bool act = (jr < 100);
  const int kb = kh ? 48 : 0;

  const float* wpI = whh + (long)(jj) * 100 + kb;
  const float* wpF = whh + (long)(100 + jj) * 100 + kb;
  const float* wpG = whh + (long)(200 + jj) * 100 + kb;
  const float* wpO = whh + (long)(300 + jj) * 100 + kb;
  f32x4 w4[4][13];
  #pragma unroll
  for (int q = 0; q < 13; ++q) {
    if (q < 12 || kh) {
      w4[0][q] = *(const f32x4*)(wpI + q * 4);
      w4[1][q] = *(const f32x4*)(wpF + q * 4);
      w4[2][q] = *(const f32x4*)(wpG + q * 4);
      w4[3][q] = *(const f32x4*)(wpO + q * 4);
    } else {
      const f32x4 z = {0.f, 0.f, 0.f, 0.f};
      w4[0][q] = z; w4[1][q] = z; w4[2][q] = z; w4[3][q] = z;
    }
  }

  const bool bwd = (dir & 1);
  const float* xq = xproj + ((long)dir * 4096 + (long)b * 128) * 400;
  u16* se = ((dir < 2) ? s1e : s2e) + (long)b * 128 * 200 + (bwd ? 100 : 0);
  float c = 0.f;
  if (tid < 104) hL[tid] = 0.f;
  float xn0, xn1, xn2, xn3;
  {
    const int ta0 = bwd ? 127 : 0;
    const float* xr = xq + (long)ta0 * 400 + jj;
    xn0 = xr[0]; xn1 = xr[100]; xn2 = xr[200]; xn3 = xr[300];
  }
  __syncthreads();

  for (int t = 0; t < 128; ++t) {
    float a0 = kh ? 0.f : xn0, a1 = kh ? 0.f : xn1;
    float a2 = kh ? 0.f : xn2, a3 = kh ? 0.f : xn3;
    #pragma unroll
    for (int q = 0; q < 13; ++q) {
      const f32x4 h4 = *(const f32x4*)&hL[kb + q * 4];
      a0 += w4[0][q][0] * h4[0]; a0 += w4[0][q][1] * h4[1];
      a0 += w4[0][q][2] * h4[2]; a0 += w4[0][q][3] * h4[3];
      a1 += w4[1][q][0] * h4[0]; a1 += w4[1][q][1] * h4[1];
      a1 += w4[1][q][2] * h4[2]; a1 += w4[1][q][3] * h4[3];
      a2 += w4[2][q][0] * h4[0]; a2 += w4[2][q][1] * h4[1];
      a2 += w4[2][q][2] * h4[2]; a2 += w4[2][q][3] * h4[3];
      a3 += w4[3][q][0] * h4[0]; a3 += w4[3][q][1] * h4[1];
      a3 += w4[3][q][2] * h4[2]; a3 += w4[3][q][3] * h4[3];
    }
    if (kh) {
      if (act) {
        const f32x4 pv = {a0, a1, a2, a3};
        *(f32x4*)&pL[jj * 4] = pv;
      }
    } else if (t + 1 < 128) {
      const int tn = bwd ? (126 - t) : (t + 1);
      const float* xr = xq + (long)tn * 400 + jj;
      xn0 = xr[0]; xn1 = xr[100]; xn2 = xr[200]; xn3 = xr[300];
    }
    wg_barrier();
    if (!kh) {
      const f32x4 p = *(const f32x4*)&pL[jj * 4];
      const float gi = a0 + p[0], gf = a1 + p[1], gg = a2 + p[2], go = a3 + p[3];
      c = sigf(gf) * c + sigf(gi) * tanhfast(gg);
      const float h = sigf(go) * tanhfast(c);
      if (act) {
        hL[jj] = h;
        const int ta = bwd ? (127 - t) : t;
        se[(long)ta * 200 + jj] = f2bf(h);
      }
    }
    wg_barrier();
  }
}

// ---------------------------------------------------------------------------
// K3: reciprocal norms rn[sent][b][l][w*20+p] = 1/max(||bf16(s_d*W_pd)||, 1e-8)
// ---------------------------------------------------------------------------
__global__ __launch_bounds__(256) void k3_norms(
    const u16* __restrict__ s1e, const u16* __restrict__ s2e,
    const float* __restrict__ W1, const float* __restrict__ W2,
    float* __restrict__ rn)
{
  const int b = blockIdx.x, lc = blockIdx.y, sent = blockIdx.z;
  const u16* se = sent ? s2e : s1e;
  #pragma unroll
  for (int it = 0; it < 5; ++it) {
    const int idx = it * 256 + (int)threadIdx.x;  // < 1280
    const int l = lc * 32 + idx / 40;
    const int pw = idx % 40;
    const float* Wp = (pw < 20) ? (W1 + pw * 200) : (W2 + (pw - 20) * 200);
    const u16* srow = se + ((long)b * 128 + l) * 200;
    float acc = 0.f;
    #pragma unroll 10
    for (int q = 0; q < 50; ++q) {
      const u16x4 sv = *(const u16x4*)(srow + q * 4);
      const f32x4 wv = *(const f32x4*)(Wp + q * 4);
      #pragma unroll
      for (int u = 0; u < 4; ++u) {
        const float pr = bf2f(f2bf(bf2f(sv[u]) * wv[u]));
        acc += pr * pr;
      }
    }
    rn[(((long)sent * 32 + b) * 128 + l) * 40 + pw] = 1.f / fmaxf(sqrtf(acc), 1e-8f);
  }
}

// ---------------------------------------------------------------------------
// K4: matching. Per (b,p,w): C = (s1.Wp)(s2.Wp)^T via 16x16x32 bf16 MFMA,
//     scale by rnu_i*rnv_j, rowmax -> s1{f,b}, colmax -> s2{f,b}.
// ---------------------------------------------------------------------------
#define LDSS 232
__global__ __launch_bounds__(256, 1) void k4_match(
    const u16* __restrict__ s1e, const u16* __restrict__ s2e,
    const float* __restrict__ W1, const float* __restrict__ W2,
    const float* __restrict__ rn, float* __restrict__ out)
{
  __shared__ __align__(16) u16 aLb[128 * LDSS];
  __shared__ __align__(16) u16 bLb[128 * LDSS];
  __shared__ float rnuL[128], rnvL[128];
  __shared__ float redA[2][128], redB[2][128];
  const int b = blockIdx.x, p = blockIdx.y, w = blockIdx.z;
  const int tid = threadIdx.x;
  const float* Wp = (w ? W2 : W1) + p * 200;
  const u16* s1r = s1e + (long)b * 128 * 200;
  const u16* s2r = s2e + (long)b * 128 * 200;

  for (int idx = tid; idx < 128 * 56; idx += 256) {
    const int row = idx / 56;
    const int k = (idx % 56) * 4;
    u16x4 oa = {0, 0, 0, 0}, ob = {0, 0, 0, 0};
    if (k < 200) {
      const u16x4 sa = *(const u16x4*)(s1r + row * 200 + k);
      const u16x4 sb = *(const u16x4*)(s2r + row * 200 + k);
      const f32x4 wv = *(const f32x4*)(Wp + k);
      #pragma unroll
      for (int u = 0; u < 4; ++u) {
        oa[u] = f2bf(bf2f(sa[u]) * wv[u]);
        ob[u] = f2bf(bf2f(sb[u]) * wv[u]);
      }
    }
    *(u16x4*)(aLb + row * LDSS + k) = oa;
    *(u16x4*)(bLb + row * LDSS + k) = ob;
  }
  if (tid < 128) {
    const int pw = w * 20 + p;
    rnuL[tid] = rn[(((long)0 * 32 + b) * 128 + tid) * 40 + pw];
    rnvL[tid] = rn[(((long)1 * 32 + b) * 128 + tid) * 40 + pw];
  }
  __syncthreads();

  const int lane = tid & 63, wvid = tid >> 6;
  const int wr = wvid >> 1, wc = wvid & 1;
  const int lr = lane & 15, kg = lane >> 4;
  f32x4 acc[4][4];
  #pragma unroll
  for (int mt = 0; mt < 4; ++mt)
    #pragma unroll
    for (int nt = 0; nt < 4; ++nt) acc[mt][nt] = 0.f;

  const u16* a0 = aLb + (64 * wr + lr) * LDSS + kg * 8;
  const u16* b0 = bLb + (64 * wc + lr) * LDSS + kg * 8;
  #pragma unroll
  for (int ks = 0; ks < 7; ++ks) {
    bf16x8 af[4], bfv[4];
    #pragma unroll
    for (int mt = 0; mt < 4; ++mt) af[mt] = *(const bf16x8*)(a0 + mt * 16 * LDSS + ks * 32);
    #pragma unroll
    for (int nt = 0; nt < 4; ++nt) bfv[nt] = *(const bf16x8*)(b0 + nt * 16 * LDSS + ks * 32);
    #pragma unroll
    for (int mt = 0; mt < 4; ++mt)
      #pragma unroll
      for (int nt = 0; nt < 4; ++nt)
        acc[mt][nt] = __builtin_amdgcn_mfma_f32_16x16x32_bf16(af[mt], bfv[nt], acc[mt][nt], 0, 0, 0);
  }

  float ru[4][4], rm[4][4], rv[4], cm[4];
  #pragma unroll
  for (int mt = 0; mt < 4; ++mt)
    #pragma unroll
    for (int r = 0; r < 4; ++r) {
      ru[mt][r] = rnuL[64 * wr + mt * 16 + kg * 4 + r];
      rm[mt][r] = -3.0e38f;
    }
  #pragma unroll
  for (int nt = 0; nt < 4; ++nt) { rv[nt] = rnvL[64 * wc + nt * 16 + lr]; cm[nt] = -3.0e38f; }
  #pragma unroll
  for (int mt = 0; mt < 4; ++mt)
    #pragma unroll
    for (int nt = 0; nt < 4; ++nt)
      #pragma unroll
      for (int r = 0; r < 4; ++r) {
        const float v = acc[mt][nt][r] * ru[mt][r] * rv[nt];
        rm[mt][r] = fmaxf(rm[mt][r], v);
        cm[nt] = fmaxf(cm[nt], v);
      }
  #pragma unroll
  for (int mt = 0; mt < 4; ++mt)
    #pragma unroll
    for (int r = 0; r < 4; ++r) {
      float v = rm[mt][r];
      v = fmaxf(v, __shfl_xor(v, 1, 64));
      v = fmaxf(v, __shfl_xor(v, 2, 64));
      v = fmaxf(v, __shfl_xor(v, 4, 64));
      v = fmaxf(v, __shfl_xor(v, 8, 64));
      rm[mt][r] = v;
    }
  #pragma unroll
  for (int nt = 0; nt < 4; ++nt) {
    float v = cm[nt];
    v = fmaxf(v, __shfl_xor(v, 16, 64));
    v = fmaxf(v, __shfl_xor(v, 32, 64));
    cm[nt] = v;
  }
  if (lr == 0) {
    #pragma unroll
    for (int mt = 0; mt < 4; ++mt)
      #pragma unroll
      for (int r = 0; r < 4; ++r) redA[wc][64 * wr + mt * 16 + kg * 4 + r] = rm[mt][r];
  }
  if (kg == 0) {
    #pragma unroll
    for (int nt = 0; nt < 4; ++nt) redB[wr][64 * wc + nt * 16 + lr] = cm[nt];
  }
  __syncthreads();
  if (tid < 128) {
    const float o1 = fmaxf(redA[0][tid], redA[1][tid]);
    const float o2 = fmaxf(redB[0][tid], redB[1][tid]);
    const long oi = ((long)b * 128 + tid) * 20 + p;
    out[(long)w * 81920 + oi] = o1;
    out[163840 + (long)w * 81920 + oi] = o2;
  }
}

// ---------------------------------------------------------------------------
extern "C" void kernel_launch(void* const* d_in, const int* in_sizes, int n_in,
                              void* d_out, int out_size, void* d_ws, size_t ws_size,
                              hipStream_t stream) {
  const int* tok1 = (const int*)d_in[0];
  const int* tok2 = (const int*)d_in[1];
  const float* embed = (const float*)d_in[2];
  const float* wih0 = (const float*)d_in[3];
  const float* whh0 = (const float*)d_in[4];
  const float* bih0 = (const float*)d_in[5];
  const float* bhh0 = (const float*)d_in[6];
  const float* wih1 = (const float*)d_in[7];
  const float* whh1 = (const float*)d_in[8];
  const float* bih1 = (const float*)d_in[9];
  const float* bhh1 = (const float*)d_in[10];
  const float* wih2 = (const float*)d_in[11];
  const float* whh2 = (const float*)d_in[12];
  const float* bih2 = (const float*)d_in[13];
  const float* bhh2 = (const float*)d_in[14];
  const float* wih3 = (const float*)d_in[15];
  const float* whh3 = (const float*)d_in[16];
  const float* bih3 = (const float*)d_in[17];
  const float* bhh3 = (const float*)d_in[18];
  const float* W1 = (const float*)d_in[19];
  const float* W2 = (const float*)d_in[20];
  float* out = (float*)d_out;

  char* ws = (char*)d_ws;
  const size_t XPROJ_B = 26214400;   // 4*4096*400*4
  const size_t SE_B = 1638400;       // 32*128*200*2
  const size_t RN_B = 1310720;       // 2*32*128*40*4
  if (ws_size < XPROJ_B + 2 * SE_B + RN_B) return;
  float* xproj = (float*)ws;
  u16* s1e = (u16*)(ws + XPROJ_B);
  u16* s2e = (u16*)(ws + XPROJ_B + SE_B);
  float* rn = (float*)(ws + XPROJ_B + 2 * SE_B);

  k1_xproj<<<dim3(32, 7, 4), 256, 0, stream>>>(
      tok1, tok2, embed, wih0, wih1, wih2, wih3,
      bih0, bih1, bih2, bih3, bhh0, bhh1, bhh2, bhh3, xproj);
  k2_lstm<<<dim3(32, 4), 256, 0, stream>>>(xproj, whh0, whh1, whh2, whh3, s1e, s2e);
  k3_norms<<<dim3(32, 4, 2), 256, 0, stream>>>(s1e, s2e, W1, W2, rn);
  k4_match<<<dim3(32, 20, 2), 256, 0, stream>>>(s1e, s2e, W1, W2, rn, out);
}